// Round 7
// baseline (768.055 us; speedup 1.0000x reference)
//
#include <hip/hip_runtime.h>
#include <hip/hip_bf16.h>
#include <stdint.h>

// Problem dims (fixed by the reference)
#define B_DIM   8192
#define LAT     256
#define MEM_DIM 200
#define NPIX    16384          // IMG*IMG = 128*128
#define RPB     16             // batch rows per block in row_kernel
#define CHUNK   25             // memory rows per LDS chunk (8 chunks x 25 = 200)

typedef short bf16x8 __attribute__((ext_vector_type(8)));
typedef float f32x4  __attribute__((ext_vector_type(4)));

__device__ __forceinline__ float wred_sum(float v) {
#pragma unroll
  for (int m = 32; m; m >>= 1) v += __shfl_xor(v, m, 64);
  return v;
}
__device__ __forceinline__ float wred_max(float v) {
#pragma unroll
  for (int m = 32; m; m >>= 1) v = fmaxf(v, __shfl_xor(v, m, 64));
  return v;
}
// round-to-nearest-even fp32 -> bf16 (bit trick; inputs are normal floats)
__device__ __forceinline__ unsigned short f2bf(float f) {
  unsigned u = __builtin_bit_cast(unsigned, f);
  u = u + 0x7FFFu + ((u >> 16) & 1u);
  return (unsigned short)(u >> 16);
}

// ---------------- memory row norms: mn[m] = ||memory[m,:]|| ----------------
__global__ void __launch_bounds__(64) mem_norm_kernel(const float* __restrict__ mem,
                                                      float* __restrict__ mn) {
  const int m = blockIdx.x, lane = threadIdx.x;
  float4 v = ((const float4*)(mem + (size_t)m * LAT))[lane];
  float ss = v.x * v.x + v.y * v.y + v.z * v.z + v.w * v.w;
  ss = wred_sum(ss);
  if (lane == 0) mn[m] = sqrtf(ss);
}

// ---------------- W fp32 -> bf16 (row-major [NPIX][LAT]) ----------------
__global__ void __launch_bounds__(256) convert_w_kernel(const float* __restrict__ W,
                                                        unsigned short* __restrict__ Wb) {
  const int i = blockIdx.x * 256 + threadIdx.x;   // quad index, grid covers exactly NPIX*LAT/4
  float4 v = ((const float4*)W)[i];
  ushort4 o;
  o.x = f2bf(v.x); o.y = f2bf(v.y); o.z = f2bf(v.z); o.w = f2bf(v.w);
  ((ushort4*)Wb)[i] = o;
}

// ---------------- fused per-row pipeline (round-6 version, unchanged) ----------------
__global__ void __launch_bounds__(256) row_kernel(
    const float* __restrict__ z, const float* __restrict__ mem,
    const float* __restrict__ mn_g, float* __restrict__ zhat_out,
    float* __restrict__ w_out, unsigned short* __restrict__ zhat_bf) {
  __shared__ float msh[CHUNK * LAT];     // 25.6 KB
  __shared__ float lw[RPB][MEM_DIM];     // 12.8 KB: raw dots, then final w
  __shared__ float mnsh[MEM_DIM];

  const int tid = threadIdx.x;
  const int lane = tid & 63;
  const int wid = tid >> 6;
  const int row0 = blockIdx.x * RPB;

  if (tid < MEM_DIM) mnsh[tid] = mn_g[tid];

  float4 zr[4];
  float zn[4];
#pragma unroll
  for (int r = 0; r < 4; ++r) {
    const int row = row0 + wid * 4 + r;
    zr[r] = *(const float4*)(z + (size_t)row * LAT + lane * 4);
    float ss = zr[r].x * zr[r].x + zr[r].y * zr[r].y + zr[r].z * zr[r].z + zr[r].w * zr[r].w;
    zn[r] = sqrtf(wred_sum(ss));
  }

  // ---- phase 1: raw dot products  lw[r][m] = z_r . mem[m] ----
#define DOT4(P, MV, R)                                                         \
  float P = (MV).x * zr[R].x + (MV).y * zr[R].y + (MV).z * zr[R].z + (MV).w * zr[R].w;

  for (int c = 0; c < 8; ++c) {
    __syncthreads();
    const float4* gsrc = (const float4*)(mem + (size_t)c * CHUNK * LAT);
    float4* msh4 = (float4*)msh;
    for (int i = tid; i < CHUNK * 64; i += 256) msh4[i] = gsrc[i];
    __syncthreads();
    for (int mm = 0; mm < CHUNK - 1; mm += 2) {
      float4 mv0 = ((float4*)msh)[(mm + 0) * 64 + lane];
      float4 mv1 = ((float4*)msh)[(mm + 1) * 64 + lane];
      DOT4(a0, mv0, 0) DOT4(a1, mv0, 1) DOT4(a2, mv0, 2) DOT4(a3, mv0, 3)
      DOT4(b0, mv1, 0) DOT4(b1, mv1, 1) DOT4(b2, mv1, 2) DOT4(b3, mv1, 3)
      a0 = wred_sum(a0); a1 = wred_sum(a1); a2 = wred_sum(a2); a3 = wred_sum(a3);
      b0 = wred_sum(b0); b1 = wred_sum(b1); b2 = wred_sum(b2); b3 = wred_sum(b3);
      if (lane == 0) {
        const int m = c * CHUNK + mm;
        lw[wid * 4 + 0][m] = a0; lw[wid * 4 + 1][m] = a1;
        lw[wid * 4 + 2][m] = a2; lw[wid * 4 + 3][m] = a3;
        lw[wid * 4 + 0][m + 1] = b0; lw[wid * 4 + 1][m + 1] = b1;
        lw[wid * 4 + 2][m + 1] = b2; lw[wid * 4 + 3][m + 1] = b3;
      }
    }
    {  // tail mm = CHUNK-1 (25 is odd)
      const int mm = CHUNK - 1;
      float4 mv0 = ((float4*)msh)[mm * 64 + lane];
      DOT4(a0, mv0, 0) DOT4(a1, mv0, 1) DOT4(a2, mv0, 2) DOT4(a3, mv0, 3)
      a0 = wred_sum(a0); a1 = wred_sum(a1); a2 = wred_sum(a2); a3 = wred_sum(a3);
      if (lane == 0) {
        const int m = c * CHUNK + mm;
        lw[wid * 4 + 0][m] = a0; lw[wid * 4 + 1][m] = a1;
        lw[wid * 4 + 2][m] = a2; lw[wid * 4 + 3][m] = a3;
      }
    }
  }
#undef DOT4
  __syncthreads();

  // ---- phase 2: cosine scale -> softmax -> shrink -> L1 normalize ----
  const float t = 0.005f;  // 1/MEM
#pragma unroll
  for (int r = 0; r < 4; ++r) {
    const int lr = wid * 4 + r;
    float lg[4];
#pragma unroll
    for (int i = 0; i < 4; ++i) {
      const int m = lane + 64 * i;
      lg[i] = (m < MEM_DIM) ? lw[lr][m] / fmaxf(zn[r] * mnsh[m], 1e-8f) : -1e30f;
    }
    float mx = wred_max(fmaxf(fmaxf(lg[0], lg[1]), fmaxf(lg[2], lg[3])));
    float e[4]; float s = 0.f;
#pragma unroll
    for (int i = 0; i < 4; ++i) {
      const int m = lane + 64 * i;
      e[i] = (m < MEM_DIM) ? expf(lg[i] - mx) : 0.f;
      s += e[i];
    }
    s = wred_sum(s);
    float sv[4]; float l1 = 0.f;
#pragma unroll
    for (int i = 0; i < 4; ++i) {
      const float wv = e[i] / s;
      const float d = wv - t;
      sv[i] = fmaxf(d, 0.f) * wv / (fabsf(d) + 1e-12f);
      l1 += sv[i];
    }
    l1 = wred_sum(l1);
    const float dnm = fmaxf(l1, 1e-12f);
#pragma unroll
    for (int i = 0; i < 4; ++i) {
      const int m = lane + 64 * i;
      if (m < MEM_DIM) {
        const float wn = sv[i] / dnm;
        lw[lr][m] = wn;
        w_out[(size_t)(row0 + lr) * MEM_DIM + m] = wn;
      }
    }
  }

  // ---- phase 3: z_hat = w @ mem ----
  f32x4 acc[4] = {};
  for (int c = 0; c < 8; ++c) {
    __syncthreads();
    const float4* gsrc = (const float4*)(mem + (size_t)c * CHUNK * LAT);
    float4* msh4 = (float4*)msh;
    for (int i = tid; i < CHUNK * 64; i += 256) msh4[i] = gsrc[i];
    __syncthreads();
    for (int mm = 0; mm < CHUNK; ++mm) {
      float4 mv = ((float4*)msh)[mm * 64 + lane];
      const int m = c * CHUNK + mm;
#pragma unroll
      for (int r = 0; r < 4; ++r) {
        const float wm = lw[wid * 4 + r][m];
        acc[r][0] += wm * mv.x; acc[r][1] += wm * mv.y;
        acc[r][2] += wm * mv.z; acc[r][3] += wm * mv.w;
      }
    }
  }
#pragma unroll
  for (int r = 0; r < 4; ++r) {
    const int row = row0 + wid * 4 + r;
    float4 o; o.x = acc[r][0]; o.y = acc[r][1]; o.z = acc[r][2]; o.w = acc[r][3];
    *(float4*)(zhat_out + (size_t)row * LAT + lane * 4) = o;
    ushort4 ob; ob.x = f2bf(o.x); ob.y = f2bf(o.y); ob.z = f2bf(o.z); ob.w = f2bf(o.w);
    *(ushort4*)(zhat_bf + (size_t)row * LAT + lane * 4) = ob;
  }
}

// ---------------- x_hat = zhat_bf @ Wb^T + bias  (UNCHANGED from round 5) ----------------
#define TSTRIDE 68   // fp32 row stride of transpose tile: 16-B aligned, 2-way-conflict-free
__global__ void __launch_bounds__(256, 3) gemm_xhat_kernel(
    const unsigned short* __restrict__ A,    // zhat bf16 [B_DIM][LAT]
    const unsigned short* __restrict__ Bw,   // W bf16 [NPIX][LAT]
    const float* __restrict__ bias,          // [NPIX]
    float* __restrict__ C) {                 // [B_DIM][NPIX]
  __shared__ __align__(16) unsigned char smem[32768];
  unsigned short* Ash0 = (unsigned short*)smem;            // [2][128*32]
  unsigned short* Bsh0 = (unsigned short*)(smem + 16384);  // [2][128*32]

  const int tid = threadIdx.x;
  const int lane = tid & 63;
  const int wid = tid >> 6;

  const int swz = (blockIdx.x & 7) * 1024 + (blockIdx.x >> 3);
  const int st = swz >> 8;
  const int loc = swz & 255;
  const int tm = (st >> 3) * 16 + (loc & 15);
  const int tn = (st & 7) * 16 + (loc >> 4);
  const int brow = tm * 128;
  const int bcol = tn * 128;

  const int wr = wid >> 1, wc = wid & 1;

  const int ch0 = wid * 2;
  const int r0 = ch0 * 16 + (lane >> 2);
  const int kq = (lane & 3) * 8;

  f32x4 acc[4][4] = {};

#define STAGE(buf, t)                                                          \
  {                                                                            \
    const int k0_ = (t) * 32;                                                  \
    _Pragma("unroll")                                                          \
    for (int cc = 0; cc < 2; ++cc) {                                           \
      const int r_ = r0 + cc * 16;                                             \
      __builtin_amdgcn_global_load_lds(                                        \
          (const __attribute__((address_space(1))) void*)(const void*)         \
              (A + (size_t)(brow + r_) * LAT + k0_ + kq),                      \
          (__attribute__((address_space(3))) void*)(void*)                     \
              &Ash0[(buf) * 4096 + (ch0 + cc) * 512], 16, 0, 0);               \
      __builtin_amdgcn_global_load_lds(                                        \
          (const __attribute__((address_space(1))) void*)(const void*)         \
              (Bw + (size_t)(bcol + r_) * LAT + k0_ + kq),                     \
          (__attribute__((address_space(3))) void*)(void*)                     \
              &Bsh0[(buf) * 4096 + (ch0 + cc) * 512], 16, 0, 0);               \
    }                                                                          \
  }

  STAGE(0, 0);
  __syncthreads();

#pragma unroll
  for (int t = 0; t < 8; ++t) {
    const int cur = t & 1;
    if (t < 7) STAGE(cur ^ 1, t + 1);

    bf16x8 af[4], bfr[4];
#pragma unroll
    for (int mf = 0; mf < 4; ++mf)
      af[mf] = *(const bf16x8*)&Ash0[cur * 4096 + (wr * 64 + mf * 16 + (lane & 15)) * 32 + ((lane >> 4) * 8)];
#pragma unroll
    for (int nf = 0; nf < 4; ++nf)
      bfr[nf] = *(const bf16x8*)&Bsh0[cur * 4096 + (wc * 64 + nf * 16 + (lane & 15)) * 32 + ((lane >> 4) * 8)];
#pragma unroll
    for (int mf = 0; mf < 4; ++mf)
#pragma unroll
      for (int nf = 0; nf < 4; ++nf)
        acc[mf][nf] = __builtin_amdgcn_mfma_f32_16x16x32_bf16(af[mf], bfr[nf], acc[mf][nf], 0, 0, 0);

    if (t < 7) __syncthreads();
  }
#undef STAGE

  // ---- epilogue: per-wave LDS transpose -> full-line dwordx4 stores ----
  __syncthreads();
  float* tt = (float*)(smem + wid * (16 * TSTRIDE * 4));

  const int colq = (lane & 15) * 4;
  const int col0 = bcol + wc * 64 + colq;
  const float4 bv4 = *(const float4*)(bias + col0);

#pragma unroll
  for (int mf = 0; mf < 4; ++mf) {
#pragma unroll
    for (int nf = 0; nf < 4; ++nf) {
      const int cl = nf * 16 + (lane & 15);
#pragma unroll
      for (int q = 0; q < 4; ++q)
        tt[((lane >> 4) * 4 + q) * TSTRIDE + cl] = acc[mf][nf][q];
    }
#pragma unroll
    for (int rr = 0; rr < 4; ++rr) {
      const int rl = rr * 4 + (lane >> 4);
      float4 v = *(const float4*)&tt[rl * TSTRIDE + colq];
      v.x += bv4.x; v.y += bv4.y; v.z += bv4.z; v.w += bv4.w;
      const int row = brow + wr * 64 + mf * 16 + rl;
      *(float4*)&C[(size_t)row * NPIX + col0] = v;
    }
  }
}

extern "C" void kernel_launch(void* const* d_in, const int* in_sizes, int n_in,
                              void* d_out, int out_size, void* d_ws, size_t ws_size,
                              hipStream_t stream) {
  const float* z    = (const float*)d_in[0];
  const float* mem  = (const float*)d_in[1];
  const float* W    = (const float*)d_in[2];
  const float* bias = (const float*)d_in[3];

  float* xhat = (float*)d_out;                       // [B_DIM][NPIX]
  float* zhat = xhat + (size_t)B_DIM * NPIX;         // [B_DIM][LAT]
  float* wout = zhat + (size_t)B_DIM * LAT;          // [B_DIM][MEM_DIM]

  unsigned short* Wb  = (unsigned short*)d_ws;
  unsigned short* zhb = Wb + (size_t)NPIX * LAT;
  float* mn = (float*)(zhb + (size_t)B_DIM * LAT);

  mem_norm_kernel<<<MEM_DIM, 64, 0, stream>>>(mem, mn);
  convert_w_kernel<<<(NPIX * LAT / 4) / 256, 256, 0, stream>>>(W, Wb);
  // INSTRUMENTATION ROUND: row_kernel launched 4x (idempotent, deterministic;
  // output unchanged). row_cost(warm) = (dur_us - 321)/3. Decision rule:
  //   dur < 440  -> row is small; attack convert/norm/gaps (fuse front-end)
  //   dur > 470  -> row dominates; m-per-lane serial-k phase-1 rewrite
  row_kernel<<<B_DIM / RPB, 256, 0, stream>>>(z, mem, mn, zhat, wout, zhb);
  row_kernel<<<B_DIM / RPB, 256, 0, stream>>>(z, mem, mn, zhat, wout, zhb);
  row_kernel<<<B_DIM / RPB, 256, 0, stream>>>(z, mem, mn, zhat, wout, zhb);
  row_kernel<<<B_DIM / RPB, 256, 0, stream>>>(z, mem, mn, zhat, wout, zhb);
  gemm_xhat_kernel<<<8192, 256, 0, stream>>>(zhb, Wb, bias, xhat);
}

// Round 9
// 223.544 us; speedup vs baseline: 3.4358x; 3.4358x over previous
//
#include <hip/hip_runtime.h>
#include <hip/hip_bf16.h>
#include <stdint.h>

// Problem dims (fixed by the reference)
#define B_DIM   8192
#define LAT     256
#define MEM_DIM 200
#define MEM_PAD 208            // padded to 13 x 16-row MFMA fragments
#define NPIX    16384          // IMG*IMG = 128*128
#define RPB     16             // batch rows per block in row_kernel
#define CHUNK   25             // memory rows per LDS chunk in phase 3 (8 x 25 = 200)

typedef short bf16x8 __attribute__((ext_vector_type(8)));
typedef float f32x4  __attribute__((ext_vector_type(4)));

__device__ __forceinline__ float wred_sum(float v) {
#pragma unroll
  for (int m = 32; m; m >>= 1) v += __shfl_xor(v, m, 64);
  return v;
}
__device__ __forceinline__ float wred_max(float v) {
#pragma unroll
  for (int m = 32; m; m >>= 1) v = fmaxf(v, __shfl_xor(v, m, 64));
  return v;
}
// round-to-nearest-even fp32 -> bf16 (bit trick; inputs are normal floats)
__device__ __forceinline__ unsigned short f2bf(float f) {
  unsigned u = __builtin_bit_cast(unsigned, f);
  u = u + 0x7FFFu + ((u >> 16) & 1u);
  return (unsigned short)(u >> 16);
}
__device__ __forceinline__ float bf2f(unsigned short h) {
  return __builtin_bit_cast(float, (unsigned)h << 16);
}
// 3-level bf16 split: v = h + m + l + r, |r| <= 2^-27 |v|  (each subtraction exact)
__device__ __forceinline__ void split3(float v, unsigned short& h, unsigned short& m,
                                       unsigned short& l) {
  h = f2bf(v);
  float r1 = v - bf2f(h);
  m = f2bf(r1);
  float r2 = r1 - bf2f(m);
  l = f2bf(r2);
}

// ---------------- memory: row norms + 3-way bf16 split (208 rows, pad zeroed) ----------------
__global__ void __launch_bounds__(64) mem_norm_kernel(const float* __restrict__ mem,
                                                      float* __restrict__ mn,
                                                      unsigned short* __restrict__ mem_h,
                                                      unsigned short* __restrict__ mem_m,
                                                      unsigned short* __restrict__ mem_l) {
  const int m = blockIdx.x, lane = threadIdx.x;
  if (m >= MEM_DIM) {                       // padding rows -> zeros
    ushort4 zz = {0, 0, 0, 0};
    ((ushort4*)(mem_h + (size_t)m * LAT))[lane] = zz;
    ((ushort4*)(mem_m + (size_t)m * LAT))[lane] = zz;
    ((ushort4*)(mem_l + (size_t)m * LAT))[lane] = zz;
    return;
  }
  float4 v = ((const float4*)(mem + (size_t)m * LAT))[lane];
  ushort4 h, md, l;
  split3(v.x, h.x, md.x, l.x); split3(v.y, h.y, md.y, l.y);
  split3(v.z, h.z, md.z, l.z); split3(v.w, h.w, md.w, l.w);
  ((ushort4*)(mem_h + (size_t)m * LAT))[lane] = h;
  ((ushort4*)(mem_m + (size_t)m * LAT))[lane] = md;
  ((ushort4*)(mem_l + (size_t)m * LAT))[lane] = l;
  float ss = v.x * v.x + v.y * v.y + v.z * v.z + v.w * v.w;
  ss = wred_sum(ss);
  if (lane == 0) mn[m] = sqrtf(ss);
}

// ---------------- z 3-way bf16 split ----------------
__global__ void __launch_bounds__(256) zsplit_kernel(const float* __restrict__ z,
                                                     unsigned short* __restrict__ z_h,
                                                     unsigned short* __restrict__ z_m,
                                                     unsigned short* __restrict__ z_l) {
  const int i = blockIdx.x * 256 + threadIdx.x;   // quad idx, grid covers B_DIM*LAT/4
  float4 v = ((const float4*)z)[i];
  ushort4 h, md, l;
  split3(v.x, h.x, md.x, l.x); split3(v.y, h.y, md.y, l.y);
  split3(v.z, h.z, md.z, l.z); split3(v.w, h.w, md.w, l.w);
  ((ushort4*)z_h)[i] = h;
  ((ushort4*)z_m)[i] = md;
  ((ushort4*)z_l)[i] = l;
}

// ---------------- W fp32 -> bf16 (row-major [NPIX][LAT]) ----------------
__global__ void __launch_bounds__(256) convert_w_kernel(const float* __restrict__ W,
                                                        unsigned short* __restrict__ Wb) {
  const int i = blockIdx.x * 256 + threadIdx.x;
  float4 v = ((const float4*)W)[i];
  ushort4 o;
  o.x = f2bf(v.x); o.y = f2bf(v.y); o.z = f2bf(v.z); o.w = f2bf(v.w);
  ((ushort4*)Wb)[i] = o;
}

// ---------------- fused per-row pipeline ----------------
// Round-9: phase-1 logits via 6-term 3-level-split MFMA (hh+hm+mh+mm+hl+lh).
// Raw-dot error ~1.2e-8 -- 8x below the empirically-safe fp32-reorder class
// (~1e-7, 7 passing rounds); round-8's bf16x3 was 3e-6 -> ~2 threshold flips.
// Phases 2/3, zn: UNCHANGED from the round-6 passing version.
__global__ void __launch_bounds__(256) row_kernel(
    const float* __restrict__ z, const float* __restrict__ mem,
    const float* __restrict__ mn_g,
    const unsigned short* __restrict__ z_h, const unsigned short* __restrict__ z_m,
    const unsigned short* __restrict__ z_l,
    const unsigned short* __restrict__ mem_h, const unsigned short* __restrict__ mem_m,
    const unsigned short* __restrict__ mem_l,
    float* __restrict__ zhat_out, float* __restrict__ w_out,
    unsigned short* __restrict__ zhat_bf) {
  __shared__ float msh[CHUNK * LAT];     // 25.6 KB (phase-3 staging)
  __shared__ float lw[RPB][MEM_DIM];     // 12.8 KB: logits, then final w
  __shared__ float mnsh[MEM_DIM];

  const int tid = threadIdx.x;
  const int lane = tid & 63;
  const int wid = tid >> 6;
  const int row0 = blockIdx.x * RPB;

  if (tid < MEM_DIM) mnsh[tid] = mn_g[tid];

  // z rows (fp32): norms (unchanged from round 6)
  float4 zr[4];
  float zn[4];
#pragma unroll
  for (int r = 0; r < 4; ++r) {
    const int row = row0 + wid * 4 + r;
    zr[r] = *(const float4*)(z + (size_t)row * LAT + lane * 4);
    float ss = zr[r].x * zr[r].x + zr[r].y * zr[r].y + zr[r].z * zr[r].z + zr[r].w * zr[r].w;
    zn[r] = sqrtf(wred_sum(ss));
  }

  // ---- phase 1: logits via 6-term split MFMA ----
  // A-frag = z rows (16 r x 32 k), B-frag = mem rows; D: col=lane&15 (m),
  // row=(lane>>4)*4+q (z-row). Wave wid handles nf = wid, wid+4, wid+8, wid+12.
  {
    const int fr_ = lane & 15;
    const int kq8 = (lane >> 4) * 8;
    const size_t zoff = (size_t)(row0 + fr_) * LAT + kq8;
    const unsigned short* zh_p = z_h + zoff;
    const unsigned short* zm_p = z_m + zoff;
    const unsigned short* zl_p = z_l + zoff;
    for (int nf = wid; nf <= 12; nf += 4) {
      const size_t moff = (size_t)(nf * 16 + fr_) * LAT + kq8;
      const unsigned short* mh_p = mem_h + moff;
      const unsigned short* mm_p = mem_m + moff;
      const unsigned short* ml_p = mem_l + moff;
      f32x4 a = {};
#pragma unroll
      for (int kk = 0; kk < 8; ++kk) {
        bf16x8 zh = *(const bf16x8*)(zh_p + kk * 32);
        bf16x8 zm = *(const bf16x8*)(zm_p + kk * 32);
        bf16x8 zl = *(const bf16x8*)(zl_p + kk * 32);
        bf16x8 mh = *(const bf16x8*)(mh_p + kk * 32);
        bf16x8 mm = *(const bf16x8*)(mm_p + kk * 32);
        bf16x8 ml = *(const bf16x8*)(ml_p + kk * 32);
        a = __builtin_amdgcn_mfma_f32_16x16x32_bf16(zm, mm, a, 0, 0, 0);  // 2^-18
        a = __builtin_amdgcn_mfma_f32_16x16x32_bf16(zh, ml, a, 0, 0, 0);  // 2^-18
        a = __builtin_amdgcn_mfma_f32_16x16x32_bf16(zl, mh, a, 0, 0, 0);  // 2^-18
        a = __builtin_amdgcn_mfma_f32_16x16x32_bf16(zm, mh, a, 0, 0, 0);  // 2^-9
        a = __builtin_amdgcn_mfma_f32_16x16x32_bf16(zh, mm, a, 0, 0, 0);  // 2^-9
        a = __builtin_amdgcn_mfma_f32_16x16x32_bf16(zh, mh, a, 0, 0, 0);  // 1
      }
      const int m = nf * 16 + fr_;
      if (m < MEM_DIM) {
#pragma unroll
        for (int q = 0; q < 4; ++q)
          lw[(lane >> 4) * 4 + q][m] = a[q];
      }
    }
  }
  __syncthreads();

  // ---- phase 2: cosine scale -> softmax -> shrink -> L1 normalize (unchanged) ----
  const float t = 0.005f;  // 1/MEM
#pragma unroll
  for (int r = 0; r < 4; ++r) {
    const int lr = wid * 4 + r;
    float lg[4];
#pragma unroll
    for (int i = 0; i < 4; ++i) {
      const int m = lane + 64 * i;
      lg[i] = (m < MEM_DIM) ? lw[lr][m] / fmaxf(zn[r] * mnsh[m], 1e-8f) : -1e30f;
    }
    float mx = wred_max(fmaxf(fmaxf(lg[0], lg[1]), fmaxf(lg[2], lg[3])));
    float e[4]; float s = 0.f;
#pragma unroll
    for (int i = 0; i < 4; ++i) {
      const int m = lane + 64 * i;
      e[i] = (m < MEM_DIM) ? expf(lg[i] - mx) : 0.f;
      s += e[i];
    }
    s = wred_sum(s);
    float sv[4]; float l1 = 0.f;
#pragma unroll
    for (int i = 0; i < 4; ++i) {
      const float wv = e[i] / s;
      const float d = wv - t;
      sv[i] = fmaxf(d, 0.f) * wv / (fabsf(d) + 1e-12f);
      l1 += sv[i];
    }
    l1 = wred_sum(l1);
    const float dnm = fmaxf(l1, 1e-12f);
#pragma unroll
    for (int i = 0; i < 4; ++i) {
      const int m = lane + 64 * i;
      if (m < MEM_DIM) {
        const float wn = sv[i] / dnm;
        lw[lr][m] = wn;
        w_out[(size_t)(row0 + lr) * MEM_DIM + m] = wn;
      }
    }
  }

  // ---- phase 3: z_hat = w @ mem (unchanged from round 6) ----
  f32x4 acc[4] = {};
  for (int c = 0; c < 8; ++c) {
    __syncthreads();
    const float4* gsrc = (const float4*)(mem + (size_t)c * CHUNK * LAT);
    float4* msh4 = (float4*)msh;
    for (int i = tid; i < CHUNK * 64; i += 256) msh4[i] = gsrc[i];
    __syncthreads();
    for (int mm = 0; mm < CHUNK; ++mm) {
      float4 mv = ((float4*)msh)[mm * 64 + lane];
      const int m = c * CHUNK + mm;
#pragma unroll
      for (int r = 0; r < 4; ++r) {
        const float wm = lw[wid * 4 + r][m];
        acc[r][0] += wm * mv.x; acc[r][1] += wm * mv.y;
        acc[r][2] += wm * mv.z; acc[r][3] += wm * mv.w;
      }
    }
  }
#pragma unroll
  for (int r = 0; r < 4; ++r) {
    const int row = row0 + wid * 4 + r;
    float4 o; o.x = acc[r][0]; o.y = acc[r][1]; o.z = acc[r][2]; o.w = acc[r][3];
    *(float4*)(zhat_out + (size_t)row * LAT + lane * 4) = o;
    ushort4 ob; ob.x = f2bf(o.x); ob.y = f2bf(o.y); ob.z = f2bf(o.z); ob.w = f2bf(o.w);
    *(ushort4*)(zhat_bf + (size_t)row * LAT + lane * 4) = ob;
  }
}

// ---------------- x_hat = zhat_bf @ Wb^T + bias  (UNCHANGED from round 5) ----------------
#define TSTRIDE 68   // fp32 row stride of transpose tile: 16-B aligned, 2-way-conflict-free
__global__ void __launch_bounds__(256, 3) gemm_xhat_kernel(
    const unsigned short* __restrict__ A,    // zhat bf16 [B_DIM][LAT]
    const unsigned short* __restrict__ Bw,   // W bf16 [NPIX][LAT]
    const float* __restrict__ bias,          // [NPIX]
    float* __restrict__ C) {                 // [B_DIM][NPIX]
  __shared__ __align__(16) unsigned char smem[32768];
  unsigned short* Ash0 = (unsigned short*)smem;            // [2][128*32]
  unsigned short* Bsh0 = (unsigned short*)(smem + 16384);  // [2][128*32]

  const int tid = threadIdx.x;
  const int lane = tid & 63;
  const int wid = tid >> 6;

  const int swz = (blockIdx.x & 7) * 1024 + (blockIdx.x >> 3);
  const int st = swz >> 8;
  const int loc = swz & 255;
  const int tm = (st >> 3) * 16 + (loc & 15);
  const int tn = (st & 7) * 16 + (loc >> 4);
  const int brow = tm * 128;
  const int bcol = tn * 128;

  const int wr = wid >> 1, wc = wid & 1;

  const int ch0 = wid * 2;
  const int r0 = ch0 * 16 + (lane >> 2);
  const int kq = (lane & 3) * 8;

  f32x4 acc[4][4] = {};

#define STAGE(buf, t)                                                          \
  {                                                                            \
    const int k0_ = (t) * 32;                                                  \
    _Pragma("unroll")                                                          \
    for (int cc = 0; cc < 2; ++cc) {                                           \
      const int r_ = r0 + cc * 16;                                             \
      __builtin_amdgcn_global_load_lds(                                        \
          (const __attribute__((address_space(1))) void*)(const void*)         \
              (A + (size_t)(brow + r_) * LAT + k0_ + kq),                      \
          (__attribute__((address_space(3))) void*)(void*)                     \
              &Ash0[(buf) * 4096 + (ch0 + cc) * 512], 16, 0, 0);               \
      __builtin_amdgcn_global_load_lds(                                        \
          (const __attribute__((address_space(1))) void*)(const void*)         \
              (Bw + (size_t)(bcol + r_) * LAT + k0_ + kq),                     \
          (__attribute__((address_space(3))) void*)(void*)                     \
              &Bsh0[(buf) * 4096 + (ch0 + cc) * 512], 16, 0, 0);               \
    }                                                                          \
  }

  STAGE(0, 0);
  __syncthreads();

#pragma unroll
  for (int t = 0; t < 8; ++t) {
    const int cur = t & 1;
    if (t < 7) STAGE(cur ^ 1, t + 1);

    bf16x8 af[4], bfr[4];
#pragma unroll
    for (int mf = 0; mf < 4; ++mf)
      af[mf] = *(const bf16x8*)&Ash0[cur * 4096 + (wr * 64 + mf * 16 + (lane & 15)) * 32 + ((lane >> 4) * 8)];
#pragma unroll
    for (int nf = 0; nf < 4; ++nf)
      bfr[nf] = *(const bf16x8*)&Bsh0[cur * 4096 + (wc * 64 + nf * 16 + (lane & 15)) * 32 + ((lane >> 4) * 8)];
#pragma unroll
    for (int mf = 0; mf < 4; ++mf)
#pragma unroll
      for (int nf = 0; nf < 4; ++nf)
        acc[mf][nf] = __builtin_amdgcn_mfma_f32_16x16x32_bf16(af[mf], bfr[nf], acc[mf][nf], 0, 0, 0);

    if (t < 7) __syncthreads();
  }
#undef STAGE

  // ---- epilogue: per-wave LDS transpose -> full-line dwordx4 stores ----
  __syncthreads();
  float* tt = (float*)(smem + wid * (16 * TSTRIDE * 4));

  const int colq = (lane & 15) * 4;
  const int col0 = bcol + wc * 64 + colq;
  const float4 bv4 = *(const float4*)(bias + col0);

#pragma unroll
  for (int mf = 0; mf < 4; ++mf) {
#pragma unroll
    for (int nf = 0; nf < 4; ++nf) {
      const int cl = nf * 16 + (lane & 15);
#pragma unroll
      for (int q = 0; q < 4; ++q)
        tt[((lane >> 4) * 4 + q) * TSTRIDE + cl] = acc[mf][nf][q];
    }
#pragma unroll
    for (int rr = 0; rr < 4; ++rr) {
      const int rl = rr * 4 + (lane >> 4);
      float4 v = *(const float4*)&tt[rl * TSTRIDE + colq];
      v.x += bv4.x; v.y += bv4.y; v.z += bv4.z; v.w += bv4.w;
      const int row = brow + wr * 64 + mf * 16 + rl;
      *(float4*)&C[(size_t)row * NPIX + col0] = v;
    }
  }
}

extern "C" void kernel_launch(void* const* d_in, const int* in_sizes, int n_in,
                              void* d_out, int out_size, void* d_ws, size_t ws_size,
                              hipStream_t stream) {
  const float* z    = (const float*)d_in[0];
  const float* mem  = (const float*)d_in[1];
  const float* W    = (const float*)d_in[2];
  const float* bias = (const float*)d_in[3];

  float* xhat = (float*)d_out;                       // [B_DIM][NPIX]
  float* zhat = xhat + (size_t)B_DIM * NPIX;         // [B_DIM][LAT]
  float* wout = zhat + (size_t)B_DIM * LAT;          // [B_DIM][MEM_DIM]

  // Split arrays live in the xhat region of d_out as scratch (13 MB << 537 MB):
  // written by split kernels, read by row_kernel, then overwritten by the GEMM.
  unsigned short* z_h   = (unsigned short*)xhat;
  unsigned short* z_m   = z_h + (size_t)B_DIM * LAT;
  unsigned short* z_l   = z_m + (size_t)B_DIM * LAT;
  unsigned short* mem_h = z_l + (size_t)B_DIM * LAT;
  unsigned short* mem_m = mem_h + (size_t)MEM_PAD * LAT;
  unsigned short* mem_l = mem_m + (size_t)MEM_PAD * LAT;

  // workspace: Wb 8.4MB | zhb 4.2MB | mn 800B  => 12.6MB
  unsigned short* Wb  = (unsigned short*)d_ws;
  unsigned short* zhb = Wb + (size_t)NPIX * LAT;
  float* mn = (float*)(zhb + (size_t)B_DIM * LAT);

  mem_norm_kernel<<<MEM_PAD, 64, 0, stream>>>(mem, mn, mem_h, mem_m, mem_l);
  zsplit_kernel<<<(B_DIM * LAT / 4) / 256, 256, 0, stream>>>(z, z_h, z_m, z_l);
  convert_w_kernel<<<(NPIX * LAT / 4) / 256, 256, 0, stream>>>(W, Wb);
  row_kernel<<<B_DIM / RPB, 256, 0, stream>>>(z, mem, mn, z_h, z_m, z_l,
                                              mem_h, mem_m, mem_l, zhat, wout, zhb);
  gemm_xhat_kernel<<<8192, 256, 0, stream>>>(zhb, Wb, bias, xhat);
}

// Round 10
// 223.374 us; speedup vs baseline: 3.4384x; 1.0008x over previous
//
#include <hip/hip_runtime.h>
#include <hip/hip_bf16.h>
#include <stdint.h>

// Problem dims (fixed by the reference)
#define B_DIM   8192
#define LAT     256
#define MEM_DIM 200
#define MEM_PAD 208            // padded to 13 x 16-row MFMA fragments
#define NPIX    16384          // IMG*IMG = 128*128
#define RPB     16             // batch rows per block in row_kernel
#define CHUNK   25             // memory rows per LDS chunk in phase 3 (8 x 25 = 200)

typedef short bf16x8 __attribute__((ext_vector_type(8)));
typedef float f32x4  __attribute__((ext_vector_type(4)));

__device__ __forceinline__ float wred_sum(float v) {
#pragma unroll
  for (int m = 32; m; m >>= 1) v += __shfl_xor(v, m, 64);
  return v;
}
__device__ __forceinline__ float wred_max(float v) {
#pragma unroll
  for (int m = 32; m; m >>= 1) v = fmaxf(v, __shfl_xor(v, m, 64));
  return v;
}
// round-to-nearest-even fp32 -> bf16 (bit trick; inputs are normal floats)
__device__ __forceinline__ unsigned short f2bf(float f) {
  unsigned u = __builtin_bit_cast(unsigned, f);
  u = u + 0x7FFFu + ((u >> 16) & 1u);
  return (unsigned short)(u >> 16);
}
__device__ __forceinline__ float bf2f(unsigned short h) {
  return __builtin_bit_cast(float, (unsigned)h << 16);
}
// 3-level bf16 split: v = h + m + l + r, |r| <= 2^-27 |v|  (each subtraction exact)
__device__ __forceinline__ void split3(float v, unsigned short& h, unsigned short& m,
                                       unsigned short& l) {
  h = f2bf(v);
  float r1 = v - bf2f(h);
  m = f2bf(r1);
  float r2 = r1 - bf2f(m);
  l = f2bf(r2);
}

// ---------------- memory: row norms + 3-way bf16 split (208 rows, pad zeroed) ----------------
__global__ void __launch_bounds__(64) mem_norm_kernel(const float* __restrict__ mem,
                                                      float* __restrict__ mn,
                                                      unsigned short* __restrict__ mem_h,
                                                      unsigned short* __restrict__ mem_m,
                                                      unsigned short* __restrict__ mem_l) {
  const int m = blockIdx.x, lane = threadIdx.x;
  if (m >= MEM_DIM) {                       // padding rows -> zeros
    ushort4 zz = {0, 0, 0, 0};
    ((ushort4*)(mem_h + (size_t)m * LAT))[lane] = zz;
    ((ushort4*)(mem_m + (size_t)m * LAT))[lane] = zz;
    ((ushort4*)(mem_l + (size_t)m * LAT))[lane] = zz;
    return;
  }
  float4 v = ((const float4*)(mem + (size_t)m * LAT))[lane];
  ushort4 h, md, l;
  split3(v.x, h.x, md.x, l.x); split3(v.y, h.y, md.y, l.y);
  split3(v.z, h.z, md.z, l.z); split3(v.w, h.w, md.w, l.w);
  ((ushort4*)(mem_h + (size_t)m * LAT))[lane] = h;
  ((ushort4*)(mem_m + (size_t)m * LAT))[lane] = md;
  ((ushort4*)(mem_l + (size_t)m * LAT))[lane] = l;
  float ss = v.x * v.x + v.y * v.y + v.z * v.z + v.w * v.w;
  ss = wred_sum(ss);
  if (lane == 0) mn[m] = sqrtf(ss);
}

// ---------------- z 3-way bf16 split ----------------
__global__ void __launch_bounds__(256) zsplit_kernel(const float* __restrict__ z,
                                                     unsigned short* __restrict__ z_h,
                                                     unsigned short* __restrict__ z_m,
                                                     unsigned short* __restrict__ z_l) {
  const int i = blockIdx.x * 256 + threadIdx.x;   // quad idx, grid covers B_DIM*LAT/4
  float4 v = ((const float4*)z)[i];
  ushort4 h, md, l;
  split3(v.x, h.x, md.x, l.x); split3(v.y, h.y, md.y, l.y);
  split3(v.z, h.z, md.z, l.z); split3(v.w, h.w, md.w, l.w);
  ((ushort4*)z_h)[i] = h;
  ((ushort4*)z_m)[i] = md;
  ((ushort4*)z_l)[i] = l;
}

// ---------------- W fp32 -> bf16 (row-major [NPIX][LAT]) ----------------
__global__ void __launch_bounds__(256) convert_w_kernel(const float* __restrict__ W,
                                                        unsigned short* __restrict__ Wb) {
  const int i = blockIdx.x * 256 + threadIdx.x;
  float4 v = ((const float4*)W)[i];
  ushort4 o;
  o.x = f2bf(v.x); o.y = f2bf(v.y); o.z = f2bf(v.z); o.w = f2bf(v.w);
  ((ushort4*)Wb)[i] = o;
}

// ---------------- fused per-row pipeline (round-9 version, UNCHANGED) ----------------
__global__ void __launch_bounds__(256) row_kernel(
    const float* __restrict__ z, const float* __restrict__ mem,
    const float* __restrict__ mn_g,
    const unsigned short* __restrict__ z_h, const unsigned short* __restrict__ z_m,
    const unsigned short* __restrict__ z_l,
    const unsigned short* __restrict__ mem_h, const unsigned short* __restrict__ mem_m,
    const unsigned short* __restrict__ mem_l,
    float* __restrict__ zhat_out, float* __restrict__ w_out,
    unsigned short* __restrict__ zhat_bf) {
  __shared__ float msh[CHUNK * LAT];     // 25.6 KB (phase-3 staging)
  __shared__ float lw[RPB][MEM_DIM];     // 12.8 KB: logits, then final w
  __shared__ float mnsh[MEM_DIM];

  const int tid = threadIdx.x;
  const int lane = tid & 63;
  const int wid = tid >> 6;
  const int row0 = blockIdx.x * RPB;

  if (tid < MEM_DIM) mnsh[tid] = mn_g[tid];

  float4 zr[4];
  float zn[4];
#pragma unroll
  for (int r = 0; r < 4; ++r) {
    const int row = row0 + wid * 4 + r;
    zr[r] = *(const float4*)(z + (size_t)row * LAT + lane * 4);
    float ss = zr[r].x * zr[r].x + zr[r].y * zr[r].y + zr[r].z * zr[r].z + zr[r].w * zr[r].w;
    zn[r] = sqrtf(wred_sum(ss));
  }

  // ---- phase 1: logits via 6-term split MFMA ----
  {
    const int fr_ = lane & 15;
    const int kq8 = (lane >> 4) * 8;
    const size_t zoff = (size_t)(row0 + fr_) * LAT + kq8;
    const unsigned short* zh_p = z_h + zoff;
    const unsigned short* zm_p = z_m + zoff;
    const unsigned short* zl_p = z_l + zoff;
    for (int nf = wid; nf <= 12; nf += 4) {
      const size_t moff = (size_t)(nf * 16 + fr_) * LAT + kq8;
      const unsigned short* mh_p = mem_h + moff;
      const unsigned short* mm_p = mem_m + moff;
      const unsigned short* ml_p = mem_l + moff;
      f32x4 a = {};
#pragma unroll
      for (int kk = 0; kk < 8; ++kk) {
        bf16x8 zh = *(const bf16x8*)(zh_p + kk * 32);
        bf16x8 zm = *(const bf16x8*)(zm_p + kk * 32);
        bf16x8 zl = *(const bf16x8*)(zl_p + kk * 32);
        bf16x8 mh = *(const bf16x8*)(mh_p + kk * 32);
        bf16x8 mm = *(const bf16x8*)(mm_p + kk * 32);
        bf16x8 ml = *(const bf16x8*)(ml_p + kk * 32);
        a = __builtin_amdgcn_mfma_f32_16x16x32_bf16(zm, mm, a, 0, 0, 0);  // 2^-18
        a = __builtin_amdgcn_mfma_f32_16x16x32_bf16(zh, ml, a, 0, 0, 0);  // 2^-18
        a = __builtin_amdgcn_mfma_f32_16x16x32_bf16(zl, mh, a, 0, 0, 0);  // 2^-18
        a = __builtin_amdgcn_mfma_f32_16x16x32_bf16(zm, mh, a, 0, 0, 0);  // 2^-9
        a = __builtin_amdgcn_mfma_f32_16x16x32_bf16(zh, mm, a, 0, 0, 0);  // 2^-9
        a = __builtin_amdgcn_mfma_f32_16x16x32_bf16(zh, mh, a, 0, 0, 0);  // 1
      }
      const int m = nf * 16 + fr_;
      if (m < MEM_DIM) {
#pragma unroll
        for (int q = 0; q < 4; ++q)
          lw[(lane >> 4) * 4 + q][m] = a[q];
      }
    }
  }
  __syncthreads();

  // ---- phase 2: cosine scale -> softmax -> shrink -> L1 normalize (unchanged) ----
  const float t = 0.005f;  // 1/MEM
#pragma unroll
  for (int r = 0; r < 4; ++r) {
    const int lr = wid * 4 + r;
    float lg[4];
#pragma unroll
    for (int i = 0; i < 4; ++i) {
      const int m = lane + 64 * i;
      lg[i] = (m < MEM_DIM) ? lw[lr][m] / fmaxf(zn[r] * mnsh[m], 1e-8f) : -1e30f;
    }
    float mx = wred_max(fmaxf(fmaxf(lg[0], lg[1]), fmaxf(lg[2], lg[3])));
    float e[4]; float s = 0.f;
#pragma unroll
    for (int i = 0; i < 4; ++i) {
      const int m = lane + 64 * i;
      e[i] = (m < MEM_DIM) ? expf(lg[i] - mx) : 0.f;
      s += e[i];
    }
    s = wred_sum(s);
    float sv[4]; float l1 = 0.f;
#pragma unroll
    for (int i = 0; i < 4; ++i) {
      const float wv = e[i] / s;
      const float d = wv - t;
      sv[i] = fmaxf(d, 0.f) * wv / (fabsf(d) + 1e-12f);
      l1 += sv[i];
    }
    l1 = wred_sum(l1);
    const float dnm = fmaxf(l1, 1e-12f);
#pragma unroll
    for (int i = 0; i < 4; ++i) {
      const int m = lane + 64 * i;
      if (m < MEM_DIM) {
        const float wn = sv[i] / dnm;
        lw[lr][m] = wn;
        w_out[(size_t)(row0 + lr) * MEM_DIM + m] = wn;
      }
    }
  }

  // ---- phase 3: z_hat = w @ mem (unchanged) ----
  f32x4 acc[4] = {};
  for (int c = 0; c < 8; ++c) {
    __syncthreads();
    const float4* gsrc = (const float4*)(mem + (size_t)c * CHUNK * LAT);
    float4* msh4 = (float4*)msh;
    for (int i = tid; i < CHUNK * 64; i += 256) msh4[i] = gsrc[i];
    __syncthreads();
    for (int mm = 0; mm < CHUNK; ++mm) {
      float4 mv = ((float4*)msh)[mm * 64 + lane];
      const int m = c * CHUNK + mm;
#pragma unroll
      for (int r = 0; r < 4; ++r) {
        const float wm = lw[wid * 4 + r][m];
        acc[r][0] += wm * mv.x; acc[r][1] += wm * mv.y;
        acc[r][2] += wm * mv.z; acc[r][3] += wm * mv.w;
      }
    }
  }
#pragma unroll
  for (int r = 0; r < 4; ++r) {
    const int row = row0 + wid * 4 + r;
    float4 o; o.x = acc[r][0]; o.y = acc[r][1]; o.z = acc[r][2]; o.w = acc[r][3];
    *(float4*)(zhat_out + (size_t)row * LAT + lane * 4) = o;
    ushort4 ob; ob.x = f2bf(o.x); ob.y = f2bf(o.y); ob.z = f2bf(o.z); ob.w = f2bf(o.w);
    *(ushort4*)(zhat_bf + (size_t)row * LAT + lane * 4) = ob;
  }
}

// ---------------- x_hat = zhat_bf @ Wb^T + bias ----------------
// Round-10 change: 3-buffer depth-3 pipelined K-loop with COUNTED vmcnt (T3/T4).
// Old: 2-buffer, full vmcnt(0) drain per __syncthreads -> stage latency exposed
// every K-step. New per-iter schedule:
//   vmcnt(counted: stage t landed) ; raw s_barrier          // buf t ready, waves aligned
//   ds_read frags(buf t) ; lgkmcnt(0) ; raw s_barrier       // all waves' reads retired
//   STAGE(t+3 -> buf t%3)                                    // overwrite is now race-free
//   16x MFMA
// Counted waits: 4 loads/wave/STAGE; in-flight {t+1,t+2} => vmcnt(8); tails 4,0.
// Staging map, MFMA order, epilogue identical to round 9 -> bitwise-same output.
#define TSTRIDE 68
__global__ void __launch_bounds__(256, 3) gemm_xhat_kernel(
    const unsigned short* __restrict__ A,    // zhat bf16 [B_DIM][LAT]
    const unsigned short* __restrict__ Bw,   // W bf16 [NPIX][LAT]
    const float* __restrict__ bias,          // [NPIX]
    float* __restrict__ C) {                 // [B_DIM][NPIX]
  // 3 stage buffers x (A 8KB + B 8KB) = 48 KB; epilogue overlays the same region.
  __shared__ __align__(16) unsigned char smem[49152];

  const int tid = threadIdx.x;
  const int lane = tid & 63;
  const int wid = tid >> 6;

  const int swz = (blockIdx.x & 7) * 1024 + (blockIdx.x >> 3);
  const int st = swz >> 8;
  const int loc = swz & 255;
  const int tm = (st >> 3) * 16 + (loc & 15);
  const int tn = (st & 7) * 16 + (loc >> 4);
  const int brow = tm * 128;
  const int bcol = tn * 128;

  const int wr = wid >> 1, wc = wid & 1;

  const int ch0 = wid * 2;
  const int r0 = ch0 * 16 + (lane >> 2);
  const int kq = (lane & 3) * 8;

  f32x4 acc[4][4] = {};

  // STAGE(bufbase_bytes, t): A chunk at bufbase + chunk*1KB, B at bufbase + 8KB + chunk*1KB
#define STAGE(bufbase, t)                                                      \
  {                                                                            \
    const int k0_ = (t) * 32;                                                  \
    _Pragma("unroll")                                                          \
    for (int cc = 0; cc < 2; ++cc) {                                           \
      const int r_ = r0 + cc * 16;                                             \
      __builtin_amdgcn_global_load_lds(                                        \
          (const __attribute__((address_space(1))) void*)(const void*)         \
              (A + (size_t)(brow + r_) * LAT + k0_ + kq),                      \
          (__attribute__((address_space(3))) void*)(void*)                     \
              &smem[(bufbase) + (ch0 + cc) * 1024], 16, 0, 0);                 \
      __builtin_amdgcn_global_load_lds(                                        \
          (const __attribute__((address_space(1))) void*)(const void*)         \
              (Bw + (size_t)(bcol + r_) * LAT + k0_ + kq),                     \
          (__attribute__((address_space(3))) void*)(void*)                     \
              &smem[(bufbase) + 8192 + (ch0 + cc) * 1024], 16, 0, 0);          \
    }                                                                          \
  }

  STAGE(0, 0);
  STAGE(16384, 1);
  STAGE(32768, 2);                 // 12 loads in flight per wave

#pragma unroll
  for (int t = 0; t < 8; ++t) {
    // wait until stage t's 4 loads retired (FIFO): {t+1,t+2} = 8 remain
    if (t < 6)       asm volatile("s_waitcnt vmcnt(8)" ::: "memory");
    else if (t == 6) asm volatile("s_waitcnt vmcnt(4)" ::: "memory");
    else             asm volatile("s_waitcnt vmcnt(0)" ::: "memory");
    __builtin_amdgcn_sched_barrier(0);
    __builtin_amdgcn_s_barrier();                 // buf t ready on ALL waves

    const int bufb = (t % 3) * 16384;             // compile-time (loop unrolled)
    bf16x8 af[4], bfr[4];
#pragma unroll
    for (int mf = 0; mf < 4; ++mf)
      af[mf] = *(const bf16x8*)&smem[bufb + (wr * 64 + mf * 16 + (lane & 15)) * 64 + (lane >> 4) * 16];
#pragma unroll
    for (int nf = 0; nf < 4; ++nf)
      bfr[nf] = *(const bf16x8*)&smem[bufb + 8192 + (wc * 64 + nf * 16 + (lane & 15)) * 64 + (lane >> 4) * 16];

    asm volatile("s_waitcnt lgkmcnt(0)" ::: "memory");   // frags in regs
    __builtin_amdgcn_sched_barrier(0);
    __builtin_amdgcn_s_barrier();                 // all waves done reading buf t

    if (t + 3 < 8) STAGE(((t + 3) % 3) * 16384, t + 3);  // safe overwrite of buf t%3

#pragma unroll
    for (int mf = 0; mf < 4; ++mf)
#pragma unroll
      for (int nf = 0; nf < 4; ++nf)
        acc[mf][nf] = __builtin_amdgcn_mfma_f32_16x16x32_bf16(af[mf], bfr[nf], acc[mf][nf], 0, 0, 0);
  }
#undef STAGE

  // ---- epilogue: per-wave LDS transpose -> full-line dwordx4 stores (unchanged) ----
  __syncthreads();
  float* tt = (float*)(smem + wid * (16 * TSTRIDE * 4));

  const int colq = (lane & 15) * 4;
  const int col0 = bcol + wc * 64 + colq;
  const float4 bv4 = *(const float4*)(bias + col0);

#pragma unroll
  for (int mf = 0; mf < 4; ++mf) {
#pragma unroll
    for (int nf = 0; nf < 4; ++nf) {
      const int cl = nf * 16 + (lane & 15);
#pragma unroll
      for (int q = 0; q < 4; ++q)
        tt[((lane >> 4) * 4 + q) * TSTRIDE + cl] = acc[mf][nf][q];
    }
#pragma unroll
    for (int rr = 0; rr < 4; ++rr) {
      const int rl = rr * 4 + (lane >> 4);
      float4 v = *(const float4*)&tt[rl * TSTRIDE + colq];
      v.x += bv4.x; v.y += bv4.y; v.z += bv4.z; v.w += bv4.w;
      const int row = brow + wr * 64 + mf * 16 + rl;
      *(float4*)&C[(size_t)row * NPIX + col0] = v;
    }
  }
}

extern "C" void kernel_launch(void* const* d_in, const int* in_sizes, int n_in,
                              void* d_out, int out_size, void* d_ws, size_t ws_size,
                              hipStream_t stream) {
  const float* z    = (const float*)d_in[0];
  const float* mem  = (const float*)d_in[1];
  const float* W    = (const float*)d_in[2];
  const float* bias = (const float*)d_in[3];

  float* xhat = (float*)d_out;                       // [B_DIM][NPIX]
  float* zhat = xhat + (size_t)B_DIM * NPIX;         // [B_DIM][LAT]
  float* wout = zhat + (size_t)B_DIM * LAT;          // [B_DIM][MEM_DIM]

  // Split arrays live in the xhat region of d_out as scratch (13 MB << 537 MB):
  // written by split kernels, read by row_kernel, then overwritten by the GEMM.
  unsigned short* z_h   = (unsigned short*)xhat;
  unsigned short* z_m   = z_h + (size_t)B_DIM * LAT;
  unsigned short* z_l   = z_m + (size_t)B_DIM * LAT;
  unsigned short* mem_h = z_l + (size_t)B_DIM * LAT;
  unsigned short* mem_m = mem_h + (size_t)MEM_PAD * LAT;
  unsigned short* mem_l = mem_m + (size_t)MEM_PAD * LAT;

  // workspace: Wb 8.4MB | zhb 4.2MB | mn 800B  => 12.6MB
  unsigned short* Wb  = (unsigned short*)d_ws;
  unsigned short* zhb = Wb + (size_t)NPIX * LAT;
  float* mn = (float*)(zhb + (size_t)B_DIM * LAT);

  mem_norm_kernel<<<MEM_PAD, 64, 0, stream>>>(mem, mn, mem_h, mem_m, mem_l);
  zsplit_kernel<<<(B_DIM * LAT / 4) / 256, 256, 0, stream>>>(z, z_h, z_m, z_l);
  convert_w_kernel<<<(NPIX * LAT / 4) / 256, 256, 0, stream>>>(W, Wb);
  row_kernel<<<B_DIM / RPB, 256, 0, stream>>>(z, mem, mn, z_h, z_m, z_l,
                                              mem_h, mem_m, mem_l, zhat, wout, zhb);
  gemm_xhat_kernel<<<8192, 256, 0, stream>>>(zhb, Wb, bias, xhat);
}